// Round 5
// baseline (302.281 us; speedup 1.0000x reference)
//
#include <hip/hip_runtime.h>
#include <hip/hip_bf16.h>

#define N_NODES 50000
#define N_EDGES 800000
#define D_FEAT  64
#define SCAN_B  256
#define SCAN_NBLK ((N_NODES + SCAN_B - 1) / SCAN_B)   // 196
#define K_REP   8        // histogram/cursor replication factor (contention / 8)
#define NPAD    50048    // padded node count per replica

// ---------------- CSR build kernels ----------------

// 8-way replicated histograms: replica r = blockIdx & 7
__global__ void hist_kernel(const int* __restrict__ src, const int* __restrict__ dst,
                            int* __restrict__ cnt_src, int* __restrict__ cnt_dst, int nE) {
    int e = blockIdx.x * blockDim.x + threadIdx.x;
    if (e < nE) {
        int r = blockIdx.x & (K_REP - 1);
        atomicAdd(&cnt_src[r * NPAD + src[e]], 1);
        atomicAdd(&cnt_dst[r * NPAD + dst[e]], 1);
    }
}

// Phase A: per-node totals (sum of 8 replicas) -> tot; block sums -> partials;
// fused dinv = rsqrt(sum of cnt_src replicas)
__global__ void scanA_kernel(const int* __restrict__ cnt_dst, const int* __restrict__ cnt_src,
                             int* __restrict__ tot, int* __restrict__ partials,
                             float* __restrict__ dinv, int n) {
    __shared__ int red[SCAN_B];
    int t = threadIdx.x;
    int idx = blockIdx.x * SCAN_B + t;
    int v = 0;
    if (idx < n) {
        int cs = 0;
        #pragma unroll
        for (int r = 0; r < K_REP; r++) {
            v  += cnt_dst[r * NPAD + idx];
            cs += cnt_src[r * NPAD + idx];
        }
        tot[idx] = v;
        dinv[idx] = (cs > 0) ? rsqrtf((float)cs) : 0.0f;
    }
    red[t] = v;
    __syncthreads();
    for (int off = SCAN_B / 2; off > 0; off >>= 1) {
        if (t < off) red[t] += red[t + off];
        __syncthreads();
    }
    if (t == 0) partials[blockIdx.x] = red[0];
}

// Phase B: single block scans NBLK partials -> exclusive blockbase; writes offs[n]=total
__global__ void scanB_kernel(const int* __restrict__ partials, int* __restrict__ blockbase,
                             int* __restrict__ offs, int n) {
    __shared__ int s[SCAN_B];
    int t = threadIdx.x;
    int v = (t < SCAN_NBLK) ? partials[t] : 0;
    s[t] = v;
    __syncthreads();
    for (int off = 1; off < SCAN_B; off <<= 1) {
        int u = (t >= off) ? s[t - off] : 0;
        __syncthreads();
        s[t] += u;
        __syncthreads();
    }
    if (t < SCAN_NBLK) blockbase[t] = (t == 0) ? 0 : s[t - 1];
    if (t == SCAN_NBLK - 1) offs[n] = s[t];
}

// Phase C: per-block exclusive scan of tot + blockbase -> offs;
// also initializes the 8 per-replica cursors to their segment bases.
__global__ void scanC_kernel(const int* __restrict__ tot, const int* __restrict__ cnt_dst,
                             const int* __restrict__ blockbase,
                             int* __restrict__ offs, int* __restrict__ cursor, int n) {
    __shared__ int s[SCAN_B];
    int t = threadIdx.x;
    int idx = blockIdx.x * SCAN_B + t;
    int v = (idx < n) ? tot[idx] : 0;
    s[t] = v;
    __syncthreads();
    for (int off = 1; off < SCAN_B; off <<= 1) {
        int u = (t >= off) ? s[t - off] : 0;
        __syncthreads();
        s[t] += u;
        __syncthreads();
    }
    if (idx < n) {
        int off0 = blockbase[blockIdx.x] + s[t] - v;   // exclusive
        offs[idx] = off0;
        int run = off0;
        #pragma unroll
        for (int r = 0; r < K_REP; r++) {
            cursor[r * NPAD + idx] = run;
            run += cnt_dst[r * NPAD + idx];
        }
    }
}

// cursor atomics pre-initialized to segment bases; atomicAdd returns the slot.
__global__ void scatter_kernel(const int* __restrict__ src, const int* __restrict__ dst,
                               int* __restrict__ cursor, int* __restrict__ csr, int nE) {
    int e = blockIdx.x * blockDim.x + threadIdx.x;
    if (e < nE) {
        int r = blockIdx.x & (K_REP - 1);
        int pos = atomicAdd(&cursor[r * NPAD + dst[e]], 1);
        csr[pos] = src[e];
    }
}

// ---------------- gather SpMM ----------------
// One wave per dst node; lane = feature column. No atomics.
// MODE 0: y=acc, h=theta*acc   MODE 1: y=acc, h+=theta*acc   MODE 2: h+=theta*acc (no y)
template <int MODE>
__global__ void spmm_csr_kernel(const int* __restrict__ offs, const int* __restrict__ csr,
                                const float* __restrict__ dinv,
                                const float* __restrict__ x,
                                float* __restrict__ y, float* __restrict__ h, float theta) {
    int wave = (blockIdx.x * blockDim.x + threadIdx.x) >> 6;
    int lane = threadIdx.x & 63;
    if (wave >= N_NODES) return;
    int i = wave;
    int b = offs[i], e2 = offs[i + 1];
    float acc = 0.0f;
    int j = b;
    for (; j + 4 <= e2; j += 4) {
        int s0 = csr[j], s1 = csr[j + 1], s2 = csr[j + 2], s3 = csr[j + 3];
        float w0 = dinv[s0], w1 = dinv[s1], w2 = dinv[s2], w3 = dinv[s3];
        float v0 = x[s0 * D_FEAT + lane];
        float v1 = x[s1 * D_FEAT + lane];
        float v2 = x[s2 * D_FEAT + lane];
        float v3 = x[s3 * D_FEAT + lane];
        acc += w0 * v0 + w1 * v1 + w2 * v2 + w3 * v3;
    }
    for (; j < e2; j++) {
        int s = csr[j];
        acc += dinv[s] * x[s * D_FEAT + lane];
    }
    acc *= dinv[i];
    int idx = i * D_FEAT + lane;
    if (MODE == 0)      { y[idx] = acc; h[idx] = theta * acc; }
    else if (MODE == 1) { y[idx] = acc; h[idx] += theta * acc; }
    else                { h[idx] += theta * acc; }
}

// ---------------- launch ----------------

extern "C" void kernel_launch(void* const* d_in, const int* in_sizes, int n_in,
                              void* d_out, int out_size, void* d_ws, size_t ws_size,
                              hipStream_t stream) {
    const float* feat = (const float*)d_in[0];
    const int*   src  = (const int*)d_in[1];
    const int*   dst  = (const int*)d_in[2];
    float* h = (float*)d_out;

    char* ws = (char*)d_ws;
    // layout (int/float elements, 4B). Build-phase arrays alias bufA (dead before SpMM1 writes it).
    //   offs:      [0, 50112)
    //   dinv:      [50112, 100160)
    //   csr:       [100160, 900160)
    //   bufA:      [900160, 4100160)     <- overlaps cnt_src/cnt_dst/cursor/tot/partials/blockbase
    //     cnt_src:   [900160, 1300544)     (8*50048)
    //     cnt_dst:   [1300544, 1700928)    (8*50048)
    //     cursor:    [1700928, 2101312)    (8*50048)
    //     tot:       [2101312, 2151360)
    //     partials:  [2151360, 2151616)
    //     blockbase: [2151616, 2151872)
    //   bufB:      [4100160, 7300160)    (total 29.2 MB)
    int*   offs      = (int*)(ws);
    float* dinv      = (float*)(ws + 50112u  * 4);
    int*   csr       = (int*)(ws + 100160u * 4);
    float* bufA      = (float*)(ws + 900160u * 4);
    int*   cnt_src   = (int*)(ws + 900160u * 4);
    int*   cnt_dst   = (int*)(ws + 1300544u * 4);
    int*   cursor    = (int*)(ws + 1700928u * 4);
    int*   tot       = (int*)(ws + 2101312u * 4);
    int*   partials  = (int*)(ws + 2151360u * 4);
    int*   blockbase = (int*)(ws + 2151616u * 4);
    float* bufB      = (float*)(ws + 4100160u * 4);

    const int nE = N_EDGES;
    const int nN = N_NODES;
    const int B = 256;

    // 1. zero both replicated histograms in one memset (cursor is written, not accumulated)
    hipMemsetAsync(cnt_src, 0, (size_t)(2 * K_REP * NPAD) * sizeof(int), stream);
    hist_kernel<<<(nE + B - 1) / B, B, 0, stream>>>(src, dst, cnt_src, cnt_dst, nE);

    // 2. parallel exclusive scan of per-node totals -> offs; dinv fused; cursors initialized
    scanA_kernel<<<SCAN_NBLK, SCAN_B, 0, stream>>>(cnt_dst, cnt_src, tot, partials, dinv, nN);
    scanB_kernel<<<1, SCAN_B, 0, stream>>>(partials, blockbase, offs, nN);
    scanC_kernel<<<SCAN_NBLK, SCAN_B, 0, stream>>>(tot, cnt_dst, blockbase, offs, cursor, nN);

    // 3. scatter edges into CSR (replicated cursors; same block-grid/r mapping as hist)
    scatter_kernel<<<(nE + B - 1) / B, B, 0, stream>>>(src, dst, cursor, csr, nE);

    // 4. three gather SpMMs, combine fused into epilogue
    const int spmmGrid = (nN * 64 + B - 1) / B;   // one wave per node
    spmm_csr_kernel<0><<<spmmGrid, B, 0, stream>>>(offs, csr, dinv, feat, bufA, h, 0.5f + 0.3f);
    spmm_csr_kernel<1><<<spmmGrid, B, 0, stream>>>(offs, csr, dinv, bufA, bufB, h, 0.15f);
    spmm_csr_kernel<2><<<spmmGrid, B, 0, stream>>>(offs, csr, dinv, bufB, nullptr, h, 0.05f);
}

// Round 8
// 281.940 us; speedup vs baseline: 1.0721x; 1.0721x over previous
//
#include <hip/hip_runtime.h>
#include <hip/hip_bf16.h>

#define N_NODES 50000
#define N_EDGES 800000
#define D_FEAT  64
#define SCAN_B  256
#define SCAN_NBLK ((N_NODES + SCAN_B - 1) / SCAN_B)   // 196
#define NB      8192     // LDS bins per range (32 KB)
#define RANGES  7        // ceil(50000/8192)
#define G_STR   32       // edge stripes
#define NPP     50000    // partial-array row length (200000 B, 16B-aligned)

// ---------------- CSR build kernels (no global atomics) ----------------

// grid (G_STR, RANGES, 2). type 0: histogram src -> psrc; type 1: dst -> pdst.
// Each block histograms its edge stripe into LDS for its bin range, then
// stores the partial counts (plain coalesced writes).
__global__ void hist_lds_kernel(const int* __restrict__ src, const int* __restrict__ dst,
                                int* __restrict__ psrc, int* __restrict__ pdst, int nE) {
    __shared__ int bins[NB];
    int t = threadIdx.x;
    for (int i = t; i < NB; i += blockDim.x) bins[i] = 0;
    __syncthreads();
    int g = blockIdx.x, range = blockIdx.y, type = blockIdx.z;
    const int* keys = (type == 0) ? src : dst;
    int lo = range * NB;
    for (int e = g * blockDim.x + t; e < nE; e += G_STR * blockDim.x) {
        unsigned k = (unsigned)(keys[e] - lo);
        if (k < NB) atomicAdd(&bins[k], 1);       // LDS atomic
    }
    __syncthreads();
    int* p = ((type == 0) ? psrc : pdst) + g * NPP;
    for (int i = t; i < NB; i += blockDim.x) {
        int node = lo + i;
        if (node < N_NODES) p[node] = bins[i];
    }
}

// Phase A: per-node totals (sum over stripes) -> tot; block sums -> partials;
// fused dinv = rsqrt(sum of psrc)
__global__ void scanA_kernel(const int* __restrict__ pdst, const int* __restrict__ psrc,
                             int* __restrict__ tot, int* __restrict__ partials,
                             float* __restrict__ dinv, int n) {
    __shared__ int red[SCAN_B];
    int t = threadIdx.x;
    int idx = blockIdx.x * SCAN_B + t;
    int v = 0;
    if (idx < n) {
        int cs = 0;
        #pragma unroll
        for (int g = 0; g < G_STR; g++) {
            v  += pdst[g * NPP + idx];
            cs += psrc[g * NPP + idx];
        }
        tot[idx] = v;
        dinv[idx] = (cs > 0) ? rsqrtf((float)cs) : 0.0f;
    }
    red[t] = v;
    __syncthreads();
    for (int off = SCAN_B / 2; off > 0; off >>= 1) {
        if (t < off) red[t] += red[t + off];
        __syncthreads();
    }
    if (t == 0) partials[blockIdx.x] = red[0];
}

// Phase B: single block scans NBLK partials -> exclusive blockbase; offs[n]=total
__global__ void scanB_kernel(const int* __restrict__ partials, int* __restrict__ blockbase,
                             int* __restrict__ offs, int n) {
    __shared__ int s[SCAN_B];
    int t = threadIdx.x;
    int v = (t < SCAN_NBLK) ? partials[t] : 0;
    s[t] = v;
    __syncthreads();
    for (int off = 1; off < SCAN_B; off <<= 1) {
        int u = (t >= off) ? s[t - off] : 0;
        __syncthreads();
        s[t] += u;
        __syncthreads();
    }
    if (t < SCAN_NBLK) blockbase[t] = (t == 0) ? 0 : s[t - 1];
    if (t == SCAN_NBLK - 1) offs[n] = s[t];
}

// Phase C: exclusive scan of tot -> offs; per-stripe slot bases gbase[g][node]
__global__ void scanC_kernel(const int* __restrict__ tot, const int* __restrict__ pdst,
                             const int* __restrict__ blockbase,
                             int* __restrict__ offs, int* __restrict__ gbase, int n) {
    __shared__ int s[SCAN_B];
    int t = threadIdx.x;
    int idx = blockIdx.x * SCAN_B + t;
    int v = (idx < n) ? tot[idx] : 0;
    s[t] = v;
    __syncthreads();
    for (int off = 1; off < SCAN_B; off <<= 1) {
        int u = (t >= off) ? s[t - off] : 0;
        __syncthreads();
        s[t] += u;
        __syncthreads();
    }
    if (idx < n) {
        int off0 = blockbase[blockIdx.x] + s[t] - v;   // exclusive
        offs[idx] = off0;
        int run = off0;
        #pragma unroll
        for (int g = 0; g < G_STR; g++) {
            gbase[g * NPP + idx] = run;
            run += pdst[g * NPP + idx];
        }
    }
}

// grid (G_STR, RANGES). LDS cursors pre-set to per-(stripe,node) bases; LDS atomic
// returns a unique CSR slot. Zero global atomics.
__global__ void scatter_lds_kernel(const int* __restrict__ src, const int* __restrict__ dst,
                                   const int* __restrict__ gbase, int* __restrict__ csr, int nE) {
    __shared__ int cur[NB];
    int t = threadIdx.x;
    int g = blockIdx.x, range = blockIdx.y;
    int lo = range * NB;
    for (int i = t; i < NB; i += blockDim.x) {
        int node = lo + i;
        cur[i] = (node < N_NODES) ? gbase[g * NPP + node] : 0;
    }
    __syncthreads();
    for (int e = g * blockDim.x + t; e < nE; e += G_STR * blockDim.x) {
        int d = dst[e];
        unsigned k = (unsigned)(d - lo);
        if (k < NB) {
            int pos = atomicAdd(&cur[k], 1);       // LDS atomic
            csr[pos] = src[e];
        }
    }
}

// ---------------- gather SpMM ----------------
// One wave per dst node; lane = feature column. No atomics.
// MODE 0: y=acc, h=theta*acc   MODE 1: y=acc, h+=theta*acc   MODE 2: h+=theta*acc
template <int MODE>
__global__ void spmm_csr_kernel(const int* __restrict__ offs, const int* __restrict__ csr,
                                const float* __restrict__ dinv,
                                const float* __restrict__ x,
                                float* __restrict__ y, float* __restrict__ h, float theta) {
    int wave = (blockIdx.x * blockDim.x + threadIdx.x) >> 6;
    int lane = threadIdx.x & 63;
    if (wave >= N_NODES) return;
    int i = wave;
    int b = offs[i], e2 = offs[i + 1];
    float acc = 0.0f;
    int j = b;
    for (; j + 4 <= e2; j += 4) {
        int s0 = csr[j], s1 = csr[j + 1], s2 = csr[j + 2], s3 = csr[j + 3];
        float w0 = dinv[s0], w1 = dinv[s1], w2 = dinv[s2], w3 = dinv[s3];
        float v0 = x[s0 * D_FEAT + lane];
        float v1 = x[s1 * D_FEAT + lane];
        float v2 = x[s2 * D_FEAT + lane];
        float v3 = x[s3 * D_FEAT + lane];
        acc += w0 * v0 + w1 * v1 + w2 * v2 + w3 * v3;
    }
    for (; j < e2; j++) {
        int s = csr[j];
        acc += dinv[s] * x[s * D_FEAT + lane];
    }
    acc *= dinv[i];
    int idx = i * D_FEAT + lane;
    if (MODE == 0)      { y[idx] = acc; h[idx] = theta * acc; }
    else if (MODE == 1) { y[idx] = acc; h[idx] += theta * acc; }
    else                { h[idx] += theta * acc; }
}

// ---------------- launch ----------------

extern "C" void kernel_launch(void* const* d_in, const int* in_sizes, int n_in,
                              void* d_out, int out_size, void* d_ws, size_t ws_size,
                              hipStream_t stream) {
    const float* feat = (const float*)d_in[0];
    const int*   src  = (const int*)d_in[1];
    const int*   dst  = (const int*)d_in[2];
    float* h = (float*)d_out;

    char* ws = (char*)d_ws;
    // layout (4B units). Partials alias bufA; gbase aliases bufB (dead before SpMMs write them):
    //   offs      [0,       50112)
    //   dinv      [50112,   100160)
    //   tot       [100160,  150208)
    //   partials  [150208,  150464)
    //   blockbase [150464,  150720)
    //   csr       [150720,  950720)
    //   bufA      [950720,  4150720)   { psrc = bufA[0:1.6M], pdst = bufA[1.6M:3.2M] }
    //   bufB      [4150720, 7350720)   { gbase = bufB[0:1.6M] }
    int*   offs      = (int*)(ws);
    float* dinv      = (float*)(ws + 50112u  * 4);
    int*   tot       = (int*)(ws + 100160u * 4);
    int*   partials  = (int*)(ws + 150208u * 4);
    int*   blockbase = (int*)(ws + 150464u * 4);
    int*   csr       = (int*)(ws + 150720u * 4);
    float* bufA      = (float*)(ws + 950720u * 4);
    int*   psrc      = (int*)(ws + 950720u * 4);
    int*   pdst      = (int*)(ws + (950720u + (unsigned)G_STR * NPP) * 4);
    float* bufB      = (float*)(ws + 4150720u * 4);
    int*   gbase     = (int*)(ws + 4150720u * 4);

    const int nE = N_EDGES;
    const int nN = N_NODES;
    const int B = 256;

    // 1. LDS-partitioned histograms of src and dst (no memset needed — partials fully written)
    dim3 histGrid(G_STR, RANGES, 2);
    hist_lds_kernel<<<histGrid, B, 0, stream>>>(src, dst, psrc, pdst, nE);

    // 2. scans: node totals + dinv; block bases; offs + per-stripe slot bases
    scanA_kernel<<<SCAN_NBLK, SCAN_B, 0, stream>>>(pdst, psrc, tot, partials, dinv, nN);
    scanB_kernel<<<1, SCAN_B, 0, stream>>>(partials, blockbase, offs, nN);
    scanC_kernel<<<SCAN_NBLK, SCAN_B, 0, stream>>>(tot, pdst, blockbase, offs, gbase, nN);

    // 3. scatter edges into CSR via LDS cursors
    dim3 scatGrid(G_STR, RANGES);
    scatter_lds_kernel<<<scatGrid, B, 0, stream>>>(src, dst, gbase, csr, nE);

    // 4. three gather SpMMs, combine fused into epilogue
    const int spmmGrid = (nN * 64 + B - 1) / B;   // one wave per node
    spmm_csr_kernel<0><<<spmmGrid, B, 0, stream>>>(offs, csr, dinv, feat, bufA, h, 0.5f + 0.3f);
    spmm_csr_kernel<1><<<spmmGrid, B, 0, stream>>>(offs, csr, dinv, bufA, bufB, h, 0.15f);
    spmm_csr_kernel<2><<<spmmGrid, B, 0, stream>>>(offs, csr, dinv, bufB, nullptr, h, 0.05f);
}

// Round 10
// 220.680 us; speedup vs baseline: 1.3698x; 1.2776x over previous
//
#include <hip/hip_runtime.h>
#include <hip/hip_bf16.h>

#define N_NODES 50000
#define N_EDGES 800000
#define D_FEAT  64
#define SCAN_B  256
#define SCAN_NBLK ((N_NODES + SCAN_B - 1) / SCAN_B)   // 196
#define NB      8192     // LDS bins per range (32 KB)
#define RANGES  7        // ceil(50000/8192)
#define G_STR   64       // edge stripes
#define NPP     50000    // partial-array row length
#define HB      512      // hist/scatter block size (8 waves)

// ---------------- CSR build kernels (no global atomics) ----------------

// grid (G_STR, RANGES, 2). type 0: histogram src -> psrc; type 1: dst -> pdst.
__global__ void hist_lds_kernel(const int* __restrict__ src, const int* __restrict__ dst,
                                int* __restrict__ psrc, int* __restrict__ pdst, int nE) {
    __shared__ int bins[NB];
    int t = threadIdx.x;
    for (int i = t; i < NB; i += HB) bins[i] = 0;
    __syncthreads();
    int g = blockIdx.x, range = blockIdx.y, type = blockIdx.z;
    const int* keys = (type == 0) ? src : dst;
    int lo = range * NB;
    for (int e = g * HB + t; e < nE; e += G_STR * HB) {
        unsigned k = (unsigned)(keys[e] - lo);
        if (k < NB) atomicAdd(&bins[k], 1);       // LDS atomic
    }
    __syncthreads();
    int* p = ((type == 0) ? psrc : pdst) + g * NPP;
    for (int i = t; i < NB; i += HB) {
        int node = lo + i;
        if (node < N_NODES) p[node] = bins[i];
    }
}

// Phase A: per-node totals (sum over stripes) -> tot; block sums -> partials;
// fused dinv = rsqrt(sum of psrc)
__global__ void scanA_kernel(const int* __restrict__ pdst, const int* __restrict__ psrc,
                             int* __restrict__ tot, int* __restrict__ partials,
                             float* __restrict__ dinv, int n) {
    __shared__ int red[SCAN_B];
    int t = threadIdx.x;
    int idx = blockIdx.x * SCAN_B + t;
    int v = 0;
    if (idx < n) {
        int cs = 0;
        #pragma unroll 16
        for (int g = 0; g < G_STR; g++) {
            v  += pdst[g * NPP + idx];
            cs += psrc[g * NPP + idx];
        }
        tot[idx] = v;
        dinv[idx] = (cs > 0) ? rsqrtf((float)cs) : 0.0f;
    }
    red[t] = v;
    __syncthreads();
    for (int off = SCAN_B / 2; off > 0; off >>= 1) {
        if (t < off) red[t] += red[t + off];
        __syncthreads();
    }
    if (t == 0) partials[blockIdx.x] = red[0];
}

// Phase B: single block scans NBLK partials -> exclusive blockbase; offs[n]=total
__global__ void scanB_kernel(const int* __restrict__ partials, int* __restrict__ blockbase,
                             int* __restrict__ offs, int n) {
    __shared__ int s[SCAN_B];
    int t = threadIdx.x;
    int v = (t < SCAN_NBLK) ? partials[t] : 0;
    s[t] = v;
    __syncthreads();
    for (int off = 1; off < SCAN_B; off <<= 1) {
        int u = (t >= off) ? s[t - off] : 0;
        __syncthreads();
        s[t] += u;
        __syncthreads();
    }
    if (t < SCAN_NBLK) blockbase[t] = (t == 0) ? 0 : s[t - 1];
    if (t == SCAN_NBLK - 1) offs[n] = s[t];
}

// Phase C: exclusive scan of tot -> offs; per-stripe slot bases gbase[g][node]
__global__ void scanC_kernel(const int* __restrict__ tot, const int* __restrict__ pdst,
                             const int* __restrict__ blockbase,
                             int* __restrict__ offs, int* __restrict__ gbase, int n) {
    __shared__ int s[SCAN_B];
    int t = threadIdx.x;
    int idx = blockIdx.x * SCAN_B + t;
    int v = (idx < n) ? tot[idx] : 0;
    s[t] = v;
    __syncthreads();
    for (int off = 1; off < SCAN_B; off <<= 1) {
        int u = (t >= off) ? s[t - off] : 0;
        __syncthreads();
        s[t] += u;
        __syncthreads();
    }
    if (idx < n) {
        int off0 = blockbase[blockIdx.x] + s[t] - v;   // exclusive
        offs[idx] = off0;
        int run = off0;
        #pragma unroll 16
        for (int g = 0; g < G_STR; g++) {
            gbase[g * NPP + idx] = run;
            run += pdst[g * NPP + idx];
        }
    }
}

// grid (G_STR, RANGES). LDS cursors pre-set to per-(stripe,node) bases.
__global__ void scatter_lds_kernel(const int* __restrict__ src, const int* __restrict__ dst,
                                   const int* __restrict__ gbase, int* __restrict__ csr, int nE) {
    __shared__ int cur[NB];
    int t = threadIdx.x;
    int g = blockIdx.x, range = blockIdx.y;
    int lo = range * NB;
    for (int i = t; i < NB; i += HB) {
        int node = lo + i;
        cur[i] = (node < N_NODES) ? gbase[g * NPP + node] : 0;
    }
    __syncthreads();
    for (int e = g * HB + t; e < nE; e += G_STR * HB) {
        int d = dst[e];
        unsigned k = (unsigned)(d - lo);
        if (k < NB) {
            int pos = atomicAdd(&cur[k], 1);       // LDS atomic
            csr[pos] = src[e];
        }
    }
}

// ---------------- gather SpMM ----------------
// One wave per dst node. Lanes: eg = lane>>4 (edge sub-slot 0..3), c4 = lane&15
// (float4 column group). 4 edges per iteration, 1 KB of x in flight per wave.
// Final 2-step shfl_xor reduces over eg. No atomics, no divergence.
// MODE 0: y=acc, h=theta*acc   MODE 1: y=acc, h+=theta*acc   MODE 2: h+=theta*acc
template <int MODE>
__global__ void spmm_csr_kernel(const int* __restrict__ offs, const int* __restrict__ csr,
                                const float* __restrict__ dinv,
                                const float* __restrict__ x,
                                float* __restrict__ y, float* __restrict__ h, float theta) {
    int i = (blockIdx.x * blockDim.x + threadIdx.x) >> 6;   // node
    if (i >= N_NODES) return;
    int lane = threadIdx.x & 63;
    int eg = lane >> 4;        // edge sub-slot
    int c4 = lane & 15;        // column group
    int b = offs[i], e2 = offs[i + 1];
    const float4* x4 = (const float4*)x;
    float ax = 0.0f, ay = 0.0f, az = 0.0f, aw = 0.0f;
    #pragma unroll 2
    for (int j = b; j < e2; j += 4) {
        int ej = j + eg;
        bool valid = ej < e2;
        int s = csr[valid ? ej : (e2 - 1)];
        float w = valid ? dinv[s] : 0.0f;
        float4 v = x4[(size_t)s * 16 + c4];
        ax += w * v.x; ay += w * v.y; az += w * v.z; aw += w * v.w;
    }
    // reduce over eg (lanes ^16, ^32)
    ax += __shfl_xor(ax, 16); ay += __shfl_xor(ay, 16);
    az += __shfl_xor(az, 16); aw += __shfl_xor(aw, 16);
    ax += __shfl_xor(ax, 32); ay += __shfl_xor(ay, 32);
    az += __shfl_xor(az, 32); aw += __shfl_xor(aw, 32);
    if (lane < 16) {
        float di = dinv[i];
        float4 acc; acc.x = ax * di; acc.y = ay * di; acc.z = az * di; acc.w = aw * di;
        size_t idx = (size_t)i * 16 + c4;
        if (MODE == 0) {
            ((float4*)y)[idx] = acc;
            float4 r; r.x = theta * acc.x; r.y = theta * acc.y;
            r.z = theta * acc.z; r.w = theta * acc.w;
            ((float4*)h)[idx] = r;
        } else if (MODE == 1) {
            ((float4*)y)[idx] = acc;
            float4 o = ((float4*)h)[idx];
            o.x += theta * acc.x; o.y += theta * acc.y;
            o.z += theta * acc.z; o.w += theta * acc.w;
            ((float4*)h)[idx] = o;
        } else {
            float4 o = ((float4*)h)[idx];
            o.x += theta * acc.x; o.y += theta * acc.y;
            o.z += theta * acc.z; o.w += theta * acc.w;
            ((float4*)h)[idx] = o;
        }
    }
}

// ---------------- launch ----------------

extern "C" void kernel_launch(void* const* d_in, const int* in_sizes, int n_in,
                              void* d_out, int out_size, void* d_ws, size_t ws_size,
                              hipStream_t stream) {
    const float* feat = (const float*)d_in[0];
    const int*   src  = (const int*)d_in[1];
    const int*   dst  = (const int*)d_in[2];
    float* h = (float*)d_out;

    char* ws = (char*)d_ws;
    // layout (4B units), total 29.4 MB. Liveness-based aliasing:
    //   psrc  = bufA  (dead after scanA)
    //   gbase = bufA  (written scanC, dead after scatter, before SpMM1 writes bufA)
    //   pdst  = bufB  (dead after scanC, before SpMM2 writes bufB)
    int*   offs      = (int*)(ws);
    float* dinv      = (float*)(ws + 50112u  * 4);
    int*   tot       = (int*)(ws + 100160u * 4);
    int*   partials  = (int*)(ws + 150208u * 4);
    int*   blockbase = (int*)(ws + 150464u * 4);
    int*   csr       = (int*)(ws + 150720u * 4);
    float* bufA      = (float*)(ws + 950720u * 4);
    int*   psrc      = (int*)(ws + 950720u * 4);
    int*   gbase     = (int*)(ws + 950720u * 4);
    float* bufB      = (float*)(ws + 4150720u * 4);
    int*   pdst      = (int*)(ws + 4150720u * 4);

    const int nE = N_EDGES;
    const int nN = N_NODES;
    const int B = 256;

    // 1. LDS-partitioned histograms of src and dst
    dim3 histGrid(G_STR, RANGES, 2);
    hist_lds_kernel<<<histGrid, HB, 0, stream>>>(src, dst, psrc, pdst, nE);

    // 2. scans: node totals + dinv; block bases; offs + per-stripe slot bases
    scanA_kernel<<<SCAN_NBLK, SCAN_B, 0, stream>>>(pdst, psrc, tot, partials, dinv, nN);
    scanB_kernel<<<1, SCAN_B, 0, stream>>>(partials, blockbase, offs, nN);
    scanC_kernel<<<SCAN_NBLK, SCAN_B, 0, stream>>>(tot, pdst, blockbase, offs, gbase, nN);

    // 3. scatter edges into CSR via LDS cursors
    dim3 scatGrid(G_STR, RANGES);
    scatter_lds_kernel<<<scatGrid, HB, 0, stream>>>(src, dst, gbase, csr, nE);

    // 4. three gather SpMMs, combine fused into epilogue
    const int spmmGrid = (nN * 64 + B - 1) / B;   // one wave per node
    spmm_csr_kernel<0><<<spmmGrid, B, 0, stream>>>(offs, csr, dinv, feat, bufA, h, 0.5f + 0.3f);
    spmm_csr_kernel<1><<<spmmGrid, B, 0, stream>>>(offs, csr, dinv, bufA, bufB, h, 0.15f);
    spmm_csr_kernel<2><<<spmmGrid, B, 0, stream>>>(offs, csr, dinv, bufB, nullptr, h, 0.05f);
}

// Round 11
// 206.387 us; speedup vs baseline: 1.4646x; 1.0693x over previous
//
#include <hip/hip_runtime.h>
#include <hip/hip_bf16.h>

#define N_NODES 50000
#define N_EDGES 800000
#define D_FEAT  64
#define SCAN_B  256
#define SCAN_NBLK ((N_NODES + SCAN_B - 1) / SCAN_B)   // 196
#define NB      8192     // LDS bins per range (32 KB)
#define RANGES  7        // ceil(50000/8192)
#define G_STR   64       // edge stripes
#define NPP     50000    // partial-array row length
#define HB      512      // hist/scatter block size (8 waves)

// ---------------- bf16 helpers ----------------
__device__ __forceinline__ float bflo(unsigned u) { return __uint_as_float(u << 16); }
__device__ __forceinline__ float bfhi(unsigned u) { return __uint_as_float(u & 0xFFFF0000u); }
__device__ __forceinline__ unsigned pack_bf16(float a, float b) {
    __hip_bfloat16 x = __float2bfloat16(a), y = __float2bfloat16(b);
    unsigned short ux = *reinterpret_cast<unsigned short*>(&x);
    unsigned short uy = *reinterpret_cast<unsigned short*>(&y);
    return (unsigned)ux | ((unsigned)uy << 16);
}

// ---------------- CSR build kernels (no global atomics) ----------------

// grid (G_STR, RANGES, 2). type 0: histogram src -> psrc; type 1: dst -> pdst.
__global__ void hist_lds_kernel(const int* __restrict__ src, const int* __restrict__ dst,
                                int* __restrict__ psrc, int* __restrict__ pdst, int nE) {
    __shared__ int bins[NB];
    int t = threadIdx.x;
    for (int i = t; i < NB; i += HB) bins[i] = 0;
    __syncthreads();
    int g = blockIdx.x, range = blockIdx.y, type = blockIdx.z;
    const int* keys = (type == 0) ? src : dst;
    int lo = range * NB;
    for (int e = g * HB + t; e < nE; e += G_STR * HB) {
        unsigned k = (unsigned)(keys[e] - lo);
        if (k < NB) atomicAdd(&bins[k], 1);       // LDS atomic
    }
    __syncthreads();
    int* p = ((type == 0) ? psrc : pdst) + g * NPP;
    for (int i = t; i < NB; i += HB) {
        int node = lo + i;
        if (node < N_NODES) p[node] = bins[i];
    }
}

// Phase A: per-node totals (sum over stripes) -> tot; block sums -> partials;
// fused dinv = rsqrt(sum of psrc)
__global__ void scanA_kernel(const int* __restrict__ pdst, const int* __restrict__ psrc,
                             int* __restrict__ tot, int* __restrict__ partials,
                             float* __restrict__ dinv, int n) {
    __shared__ int red[SCAN_B];
    int t = threadIdx.x;
    int idx = blockIdx.x * SCAN_B + t;
    int v = 0;
    if (idx < n) {
        int cs = 0;
        #pragma unroll 16
        for (int g = 0; g < G_STR; g++) {
            v  += pdst[g * NPP + idx];
            cs += psrc[g * NPP + idx];
        }
        tot[idx] = v;
        dinv[idx] = (cs > 0) ? rsqrtf((float)cs) : 0.0f;
    }
    red[t] = v;
    __syncthreads();
    for (int off = SCAN_B / 2; off > 0; off >>= 1) {
        if (t < off) red[t] += red[t + off];
        __syncthreads();
    }
    if (t == 0) partials[blockIdx.x] = red[0];
}

// Phase B: single block scans NBLK partials -> exclusive blockbase; offs[n]=total
__global__ void scanB_kernel(const int* __restrict__ partials, int* __restrict__ blockbase,
                             int* __restrict__ offs, int n) {
    __shared__ int s[SCAN_B];
    int t = threadIdx.x;
    int v = (t < SCAN_NBLK) ? partials[t] : 0;
    s[t] = v;
    __syncthreads();
    for (int off = 1; off < SCAN_B; off <<= 1) {
        int u = (t >= off) ? s[t - off] : 0;
        __syncthreads();
        s[t] += u;
        __syncthreads();
    }
    if (t < SCAN_NBLK) blockbase[t] = (t == 0) ? 0 : s[t - 1];
    if (t == SCAN_NBLK - 1) offs[n] = s[t];
}

// Phase C: exclusive scan of tot -> offs; per-stripe slot bases gbase[g][node]
__global__ void scanC_kernel(const int* __restrict__ tot, const int* __restrict__ pdst,
                             const int* __restrict__ blockbase,
                             int* __restrict__ offs, int* __restrict__ gbase, int n) {
    __shared__ int s[SCAN_B];
    int t = threadIdx.x;
    int idx = blockIdx.x * SCAN_B + t;
    int v = (idx < n) ? tot[idx] : 0;
    s[t] = v;
    __syncthreads();
    for (int off = 1; off < SCAN_B; off <<= 1) {
        int u = (t >= off) ? s[t - off] : 0;
        __syncthreads();
        s[t] += u;
        __syncthreads();
    }
    if (idx < n) {
        int off0 = blockbase[blockIdx.x] + s[t] - v;   // exclusive
        offs[idx] = off0;
        int run = off0;
        #pragma unroll 16
        for (int g = 0; g < G_STR; g++) {
            gbase[g * NPP + idx] = run;
            run += pdst[g * NPP + idx];
        }
    }
}

// grid (G_STR, RANGES). Writes fused (src, dinv[src]) entries.
__global__ void scatter_lds_kernel(const int* __restrict__ src, const int* __restrict__ dst,
                                   const int* __restrict__ gbase, const float* __restrict__ dinv,
                                   int2* __restrict__ csr2, int nE) {
    __shared__ int cur[NB];
    int t = threadIdx.x;
    int g = blockIdx.x, range = blockIdx.y;
    int lo = range * NB;
    for (int i = t; i < NB; i += HB) {
        int node = lo + i;
        cur[i] = (node < N_NODES) ? gbase[g * NPP + node] : 0;
    }
    __syncthreads();
    for (int e = g * HB + t; e < nE; e += G_STR * HB) {
        int d = dst[e];
        unsigned k = (unsigned)(d - lo);
        if (k < NB) {
            int pos = atomicAdd(&cur[k], 1);       // LDS atomic
            int s = src[e];
            csr2[pos] = make_int2(s, __float_as_int(dinv[s]));
        }
    }
}

// feat f32 -> bf16 (packed), 3.2M elements
__global__ void convert_kernel(const float* __restrict__ feat, unsigned* __restrict__ out, int n4) {
    int i = blockIdx.x * blockDim.x + threadIdx.x;
    if (i < n4) {
        float4 v = ((const float4*)feat)[i];
        out[2 * i]     = pack_bf16(v.x, v.y);
        out[2 * i + 1] = pack_bf16(v.z, v.w);
    }
}

// ---------------- gather SpMM (bf16 x, f32 accumulate) ----------------
// One wave per dst node. Lanes: eg = lane>>3 (edge slot 0..7), c8 = lane&7
// (16B column group). 8 edges in flight per iteration; csr2 gives (s, w) in
// one sequential 8B load (no dependent dinv gather). Reduce over eg via
// shfl_xor 8/16/32. Epilogue: lanes 0..7 own columns c8*8..c8*8+7.
// MODE 0: y=acc, h=theta*acc   MODE 1: y=acc, h+=theta*acc   MODE 2: h+=theta*acc
template <int MODE>
__global__ void spmm_bf16_kernel(const int* __restrict__ offs, const int2* __restrict__ csr2,
                                 const float* __restrict__ dinv,
                                 const unsigned* __restrict__ x,   // bf16 rows, 32 words/row
                                 unsigned* __restrict__ y,         // bf16 out rows
                                 float* __restrict__ h, float theta) {
    int i = (blockIdx.x * blockDim.x + threadIdx.x) >> 6;   // node
    if (i >= N_NODES) return;
    int lane = threadIdx.x & 63;
    int eg = lane >> 3;        // edge sub-slot 0..7
    int c8 = lane & 7;         // 16B column group 0..7
    int b = offs[i], e2 = offs[i + 1];
    const uint4* x4 = (const uint4*)x;
    float a0 = 0, a1 = 0, a2 = 0, a3 = 0, a4 = 0, a5 = 0, a6 = 0, a7 = 0;
    #pragma unroll 2
    for (int j = b; j < e2; j += 8) {
        int ej = j + eg;
        bool valid = ej < e2;
        int2 sw = csr2[valid ? ej : (e2 - 1)];
        float w = valid ? __int_as_float(sw.y) : 0.0f;
        uint4 r = x4[(size_t)sw.x * 8 + c8];
        a0 += w * bflo(r.x); a1 += w * bfhi(r.x);
        a2 += w * bflo(r.y); a3 += w * bfhi(r.y);
        a4 += w * bflo(r.z); a5 += w * bfhi(r.z);
        a6 += w * bflo(r.w); a7 += w * bfhi(r.w);
    }
    #pragma unroll
    for (int d = 8; d <= 32; d <<= 1) {
        a0 += __shfl_xor(a0, d); a1 += __shfl_xor(a1, d);
        a2 += __shfl_xor(a2, d); a3 += __shfl_xor(a3, d);
        a4 += __shfl_xor(a4, d); a5 += __shfl_xor(a5, d);
        a6 += __shfl_xor(a6, d); a7 += __shfl_xor(a7, d);
    }
    if (lane < 8) {
        float di = dinv[i];
        a0 *= di; a1 *= di; a2 *= di; a3 *= di;
        a4 *= di; a5 *= di; a6 *= di; a7 *= di;
        size_t hbase = (size_t)i * 16 + (size_t)c8 * 2;   // float4 index into h
        float4* h4 = (float4*)h;
        if (MODE == 0) {
            float4 r0; r0.x = theta * a0; r0.y = theta * a1; r0.z = theta * a2; r0.w = theta * a3;
            float4 r1; r1.x = theta * a4; r1.y = theta * a5; r1.z = theta * a6; r1.w = theta * a7;
            h4[hbase] = r0; h4[hbase + 1] = r1;
        } else {
            float4 o0 = h4[hbase], o1 = h4[hbase + 1];
            o0.x += theta * a0; o0.y += theta * a1; o0.z += theta * a2; o0.w += theta * a3;
            o1.x += theta * a4; o1.y += theta * a5; o1.z += theta * a6; o1.w += theta * a7;
            h4[hbase] = o0; h4[hbase + 1] = o1;
        }
        if (MODE != 2) {
            uint4 p;
            p.x = pack_bf16(a0, a1); p.y = pack_bf16(a2, a3);
            p.z = pack_bf16(a4, a5); p.w = pack_bf16(a6, a7);
            ((uint4*)y)[(size_t)i * 8 + c8] = p;
        }
    }
}

// ---------------- launch ----------------

extern "C" void kernel_launch(void* const* d_in, const int* in_sizes, int n_in,
                              void* d_out, int out_size, void* d_ws, size_t ws_size,
                              hipStream_t stream) {
    const float* feat = (const float*)d_in[0];
    const int*   src  = (const int*)d_in[1];
    const int*   dst  = (const int*)d_in[2];
    float* h = (float*)d_out;

    char* ws = (char*)d_ws;
    // layout (4B words), total 45.4 MB. Liveness aliasing:
    //   P1: psrc (dead after scanA)  -> bufA  (bf16 x1, 1.6M words)
    //   P2: pdst (dead after scanC)  -> bufB  (bf16 x2)
    //   P3: gbase (dead after scatter)-> featbf (bf16 feat)
    int*      offs      = (int*)(ws);                       // [0, 50112)
    float*    dinv      = (float*)(ws + 50112u  * 4);       // [50112, 100160)
    int*      tot       = (int*)(ws + 100160u * 4);         // [100160, 150208)
    int*      partials  = (int*)(ws + 150208u * 4);
    int*      blockbase = (int*)(ws + 150464u * 4);
    int2*     csr2      = (int2*)(ws + 150720u * 4);        // 1.6M words
    int*      psrc      = (int*)(ws + 1750720u * 4);        // P1: 3.2M words
    unsigned* bufA      = (unsigned*)(ws + 1750720u * 4);
    int*      pdst      = (int*)(ws + 4950720u * 4);        // P2: 3.2M words
    unsigned* bufB      = (unsigned*)(ws + 4950720u * 4);
    int*      gbase     = (int*)(ws + 8150720u * 4);        // P3: 3.2M words
    unsigned* featbf    = (unsigned*)(ws + 8150720u * 4);

    const int nE = N_EDGES;
    const int nN = N_NODES;
    const int B = 256;

    // 1. LDS-partitioned histograms of src and dst
    dim3 histGrid(G_STR, RANGES, 2);
    hist_lds_kernel<<<histGrid, HB, 0, stream>>>(src, dst, psrc, pdst, nE);

    // 2. scans: node totals + dinv; block bases; offs + per-stripe slot bases
    scanA_kernel<<<SCAN_NBLK, SCAN_B, 0, stream>>>(pdst, psrc, tot, partials, dinv, nN);
    scanB_kernel<<<1, SCAN_B, 0, stream>>>(partials, blockbase, offs, nN);
    scanC_kernel<<<SCAN_NBLK, SCAN_B, 0, stream>>>(tot, pdst, blockbase, offs, gbase, nN);

    // 3. scatter edges into fused (src, w) CSR via LDS cursors
    dim3 scatGrid(G_STR, RANGES);
    scatter_lds_kernel<<<scatGrid, HB, 0, stream>>>(src, dst, gbase, dinv, csr2, nE);

    // 4. feat f32 -> bf16 (after scatter: featbf aliases gbase)
    convert_kernel<<<(nN * D_FEAT / 4 + B - 1) / B, B, 0, stream>>>(feat, featbf, nN * D_FEAT / 4);

    // 5. three gather SpMMs, combine fused into epilogue
    const int spmmGrid = (nN * 64 + B - 1) / B;   // one wave per node
    spmm_bf16_kernel<0><<<spmmGrid, B, 0, stream>>>(offs, csr2, dinv, featbf, bufA, h, 0.5f + 0.3f);
    spmm_bf16_kernel<1><<<spmmGrid, B, 0, stream>>>(offs, csr2, dinv, bufA, bufB, h, 0.15f);
    spmm_bf16_kernel<2><<<spmmGrid, B, 0, stream>>>(offs, csr2, dinv, bufB, nullptr, h, 0.05f);
}

// Round 12
// 205.099 us; speedup vs baseline: 1.4738x; 1.0063x over previous
//
#include <hip/hip_runtime.h>
#include <hip/hip_bf16.h>

#define N_NODES 50000
#define N_EDGES 800000
#define D_FEAT  64
#define SCAN_B  256
#define SCAN_NBLK ((N_NODES + SCAN_B - 1) / SCAN_B)   // 196
#define NB      12800    // LDS bins per range (50 KB -> 3 blocks/CU)
#define RANGES  4        // ceil(50000/12800)
#define G_STR   64       // edge stripes
#define NPP     50000    // partial-array row length
#define HB      512      // hist/scatter block size (8 waves)

// ---------------- bf16 helpers ----------------
__device__ __forceinline__ float bflo(unsigned u) { return __uint_as_float(u << 16); }
__device__ __forceinline__ float bfhi(unsigned u) { return __uint_as_float(u & 0xFFFF0000u); }
__device__ __forceinline__ unsigned pack_bf16(float a, float b) {
    __hip_bfloat16 x = __float2bfloat16(a), y = __float2bfloat16(b);
    unsigned short ux = *reinterpret_cast<unsigned short*>(&x);
    unsigned short uy = *reinterpret_cast<unsigned short*>(&y);
    return (unsigned)ux | ((unsigned)uy << 16);
}

// ---------------- CSR build kernels (no global atomics) ----------------

// grid (G_STR, RANGES, 2). type 0: histogram src -> psrc; type 1: dst -> pdst.
__global__ void hist_lds_kernel(const int* __restrict__ src, const int* __restrict__ dst,
                                int* __restrict__ psrc, int* __restrict__ pdst, int nE) {
    __shared__ int bins[NB];
    int t = threadIdx.x;
    for (int i = t; i < NB; i += HB) bins[i] = 0;
    __syncthreads();
    int g = blockIdx.x, range = blockIdx.y, type = blockIdx.z;
    const int* keys = (type == 0) ? src : dst;
    int lo = range * NB;
    for (int e = g * HB + t; e < nE; e += G_STR * HB) {
        unsigned k = (unsigned)(keys[e] - lo);
        if (k < NB) atomicAdd(&bins[k], 1);       // LDS atomic
    }
    __syncthreads();
    int* p = ((type == 0) ? psrc : pdst) + g * NPP;
    for (int i = t; i < NB; i += HB) {
        int node = lo + i;
        if (node < N_NODES) p[node] = bins[i];
    }
}

// Phase A: per-node totals (sum over stripes) -> tot; block sums -> partials;
// fused dinv = rsqrt(sum of psrc)
__global__ void scanA_kernel(const int* __restrict__ pdst, const int* __restrict__ psrc,
                             int* __restrict__ tot, int* __restrict__ partials,
                             float* __restrict__ dinv, int n) {
    __shared__ int red[SCAN_B];
    int t = threadIdx.x;
    int idx = blockIdx.x * SCAN_B + t;
    int v = 0;
    if (idx < n) {
        int cs = 0;
        #pragma unroll 16
        for (int g = 0; g < G_STR; g++) {
            v  += pdst[g * NPP + idx];
            cs += psrc[g * NPP + idx];
        }
        tot[idx] = v;
        dinv[idx] = (cs > 0) ? rsqrtf((float)cs) : 0.0f;
    }
    red[t] = v;
    __syncthreads();
    for (int off = SCAN_B / 2; off > 0; off >>= 1) {
        if (t < off) red[t] += red[t + off];
        __syncthreads();
    }
    if (t == 0) partials[blockIdx.x] = red[0];
}

// Phase B: single block scans NBLK partials -> exclusive blockbase; offs[n]=total
__global__ void scanB_kernel(const int* __restrict__ partials, int* __restrict__ blockbase,
                             int* __restrict__ offs, int n) {
    __shared__ int s[SCAN_B];
    int t = threadIdx.x;
    int v = (t < SCAN_NBLK) ? partials[t] : 0;
    s[t] = v;
    __syncthreads();
    for (int off = 1; off < SCAN_B; off <<= 1) {
        int u = (t >= off) ? s[t - off] : 0;
        __syncthreads();
        s[t] += u;
        __syncthreads();
    }
    if (t < SCAN_NBLK) blockbase[t] = (t == 0) ? 0 : s[t - 1];
    if (t == SCAN_NBLK - 1) offs[n] = s[t];
}

// Phase C: exclusive scan of tot -> offs; per-stripe slot bases gbase[g][node]
__global__ void scanC_kernel(const int* __restrict__ tot, const int* __restrict__ pdst,
                             const int* __restrict__ blockbase,
                             int* __restrict__ offs, int* __restrict__ gbase, int n) {
    __shared__ int s[SCAN_B];
    int t = threadIdx.x;
    int idx = blockIdx.x * SCAN_B + t;
    int v = (idx < n) ? tot[idx] : 0;
    s[t] = v;
    __syncthreads();
    for (int off = 1; off < SCAN_B; off <<= 1) {
        int u = (t >= off) ? s[t - off] : 0;
        __syncthreads();
        s[t] += u;
        __syncthreads();
    }
    if (idx < n) {
        int off0 = blockbase[blockIdx.x] + s[t] - v;   // exclusive
        offs[idx] = off0;
        int run = off0;
        #pragma unroll 16
        for (int g = 0; g < G_STR; g++) {
            gbase[g * NPP + idx] = run;
            run += pdst[g * NPP + idx];
        }
    }
}

// grid (G_STR, RANGES). Writes fused (src, dinv[src]) entries.
__global__ void scatter_lds_kernel(const int* __restrict__ src, const int* __restrict__ dst,
                                   const int* __restrict__ gbase, const float* __restrict__ dinv,
                                   int2* __restrict__ csr2, int nE) {
    __shared__ int cur[NB];
    int t = threadIdx.x;
    int g = blockIdx.x, range = blockIdx.y;
    int lo = range * NB;
    for (int i = t; i < NB; i += HB) {
        int node = lo + i;
        cur[i] = (node < N_NODES) ? gbase[g * NPP + node] : 0;
    }
    __syncthreads();
    for (int e = g * HB + t; e < nE; e += G_STR * HB) {
        int d = dst[e];
        unsigned k = (unsigned)(d - lo);
        if (k < NB) {
            int pos = atomicAdd(&cur[k], 1);       // LDS atomic
            int s = src[e];
            csr2[pos] = make_int2(s, __float_as_int(dinv[s]));
        }
    }
}

// feat f32 -> bf16 (packed), 3.2M elements
__global__ void convert_kernel(const float* __restrict__ feat, unsigned* __restrict__ out, int n4) {
    int i = blockIdx.x * blockDim.x + threadIdx.x;
    if (i < n4) {
        float4 v = ((const float4*)feat)[i];
        out[2 * i]     = pack_bf16(v.x, v.y);
        out[2 * i + 1] = pack_bf16(v.z, v.w);
    }
}

// ---------------- gather SpMM (bf16 x, f32 accumulate) ----------------
// One wave per dst node. Lanes: eg = lane>>3 (edge slot 0..7), c8 = lane&7
// (16B column group). 16 edges in flight per iteration (2 csr2 + 2 row loads
// per lane); avg-degree-16 nodes finish in ONE iteration. Reduce over eg via
// shfl_xor 8/16/32. Epilogue: lanes 0..7 own columns c8*8..c8*8+7.
// MODE 0: y=acc, h=theta*acc   MODE 1: y=acc, h+=theta*acc   MODE 2: h+=theta*acc
template <int MODE>
__global__ void spmm_bf16_kernel(const int* __restrict__ offs, const int2* __restrict__ csr2,
                                 const float* __restrict__ dinv,
                                 const unsigned* __restrict__ x,   // bf16 rows, 32 words/row
                                 unsigned* __restrict__ y,         // bf16 out rows
                                 float* __restrict__ h, float theta) {
    int i = (blockIdx.x * blockDim.x + threadIdx.x) >> 6;   // node
    if (i >= N_NODES) return;
    int lane = threadIdx.x & 63;
    int eg = lane >> 3;        // edge sub-slot 0..7
    int c8 = lane & 7;         // 16B column group 0..7
    int b = offs[i], e2 = offs[i + 1];
    const uint4* x4 = (const uint4*)x;
    float a0 = 0, a1 = 0, a2 = 0, a3 = 0, a4 = 0, a5 = 0, a6 = 0, a7 = 0;
    for (int j = b; j < e2; j += 16) {
        int ej0 = j + eg, ej1 = j + 8 + eg;
        bool v0 = ej0 < e2, v1 = ej1 < e2;
        int2 sw0 = csr2[v0 ? ej0 : (e2 - 1)];
        int2 sw1 = csr2[v1 ? ej1 : (e2 - 1)];
        float w0 = v0 ? __int_as_float(sw0.y) : 0.0f;
        float w1 = v1 ? __int_as_float(sw1.y) : 0.0f;
        uint4 r0 = x4[(size_t)sw0.x * 8 + c8];
        uint4 r1 = x4[(size_t)sw1.x * 8 + c8];
        a0 += w0 * bflo(r0.x) + w1 * bflo(r1.x);
        a1 += w0 * bfhi(r0.x) + w1 * bfhi(r1.x);
        a2 += w0 * bflo(r0.y) + w1 * bflo(r1.y);
        a3 += w0 * bfhi(r0.y) + w1 * bfhi(r1.y);
        a4 += w0 * bflo(r0.z) + w1 * bflo(r1.z);
        a5 += w0 * bfhi(r0.z) + w1 * bfhi(r1.z);
        a6 += w0 * bflo(r0.w) + w1 * bflo(r1.w);
        a7 += w0 * bfhi(r0.w) + w1 * bfhi(r1.w);
    }
    #pragma unroll
    for (int d = 8; d <= 32; d <<= 1) {
        a0 += __shfl_xor(a0, d); a1 += __shfl_xor(a1, d);
        a2 += __shfl_xor(a2, d); a3 += __shfl_xor(a3, d);
        a4 += __shfl_xor(a4, d); a5 += __shfl_xor(a5, d);
        a6 += __shfl_xor(a6, d); a7 += __shfl_xor(a7, d);
    }
    if (lane < 8) {
        float di = dinv[i];
        a0 *= di; a1 *= di; a2 *= di; a3 *= di;
        a4 *= di; a5 *= di; a6 *= di; a7 *= di;
        size_t hbase = (size_t)i * 16 + (size_t)c8 * 2;   // float4 index into h
        float4* h4 = (float4*)h;
        if (MODE == 0) {
            float4 r0; r0.x = theta * a0; r0.y = theta * a1; r0.z = theta * a2; r0.w = theta * a3;
            float4 r1; r1.x = theta * a4; r1.y = theta * a5; r1.z = theta * a6; r1.w = theta * a7;
            h4[hbase] = r0; h4[hbase + 1] = r1;
        } else {
            float4 o0 = h4[hbase], o1 = h4[hbase + 1];
            o0.x += theta * a0; o0.y += theta * a1; o0.z += theta * a2; o0.w += theta * a3;
            o1.x += theta * a4; o1.y += theta * a5; o1.z += theta * a6; o1.w += theta * a7;
            h4[hbase] = o0; h4[hbase + 1] = o1;
        }
        if (MODE != 2) {
            uint4 p;
            p.x = pack_bf16(a0, a1); p.y = pack_bf16(a2, a3);
            p.z = pack_bf16(a4, a5); p.w = pack_bf16(a6, a7);
            ((uint4*)y)[(size_t)i * 8 + c8] = p;
        }
    }
}

// ---------------- launch ----------------

extern "C" void kernel_launch(void* const* d_in, const int* in_sizes, int n_in,
                              void* d_out, int out_size, void* d_ws, size_t ws_size,
                              hipStream_t stream) {
    const float* feat = (const float*)d_in[0];
    const int*   src  = (const int*)d_in[1];
    const int*   dst  = (const int*)d_in[2];
    float* h = (float*)d_out;

    char* ws = (char*)d_ws;
    // layout (4B words), total 45.4 MB. Liveness aliasing:
    //   P1: psrc (dead after scanA)  -> bufA  (bf16 x1, 1.6M words)
    //   P2: pdst (dead after scanC)  -> bufB  (bf16 x2)
    //   P3: gbase (dead after scatter)-> featbf (bf16 feat)
    int*      offs      = (int*)(ws);                       // [0, 50112)
    float*    dinv      = (float*)(ws + 50112u  * 4);       // [50112, 100160)
    int*      tot       = (int*)(ws + 100160u * 4);         // [100160, 150208)
    int*      partials  = (int*)(ws + 150208u * 4);
    int*      blockbase = (int*)(ws + 150464u * 4);
    int2*     csr2      = (int2*)(ws + 150720u * 4);        // 1.6M words
    int*      psrc      = (int*)(ws + 1750720u * 4);        // P1: 3.2M words
    unsigned* bufA      = (unsigned*)(ws + 1750720u * 4);
    int*      pdst      = (int*)(ws + 4950720u * 4);        // P2: 3.2M words
    unsigned* bufB      = (unsigned*)(ws + 4950720u * 4);
    int*      gbase     = (int*)(ws + 8150720u * 4);        // P3: 3.2M words
    unsigned* featbf    = (unsigned*)(ws + 8150720u * 4);

    const int nE = N_EDGES;
    const int nN = N_NODES;
    const int B = 256;

    // 1. LDS-partitioned histograms of src and dst (4 ranges x 64 stripes)
    dim3 histGrid(G_STR, RANGES, 2);
    hist_lds_kernel<<<histGrid, HB, 0, stream>>>(src, dst, psrc, pdst, nE);

    // 2. scans: node totals + dinv; block bases; offs + per-stripe slot bases
    scanA_kernel<<<SCAN_NBLK, SCAN_B, 0, stream>>>(pdst, psrc, tot, partials, dinv, nN);
    scanB_kernel<<<1, SCAN_B, 0, stream>>>(partials, blockbase, offs, nN);
    scanC_kernel<<<SCAN_NBLK, SCAN_B, 0, stream>>>(tot, pdst, blockbase, offs, gbase, nN);

    // 3. scatter edges into fused (src, w) CSR via LDS cursors
    dim3 scatGrid(G_STR, RANGES);
    scatter_lds_kernel<<<scatGrid, HB, 0, stream>>>(src, dst, gbase, dinv, csr2, nE);

    // 4. feat f32 -> bf16 (after scatter: featbf aliases gbase)
    convert_kernel<<<(nN * D_FEAT / 4 + B - 1) / B, B, 0, stream>>>(feat, featbf, nN * D_FEAT / 4);

    // 5. three gather SpMMs, combine fused into epilogue
    const int spmmGrid = (nN * 64 + B - 1) / B;   // one wave per node
    spmm_bf16_kernel<0><<<spmmGrid, B, 0, stream>>>(offs, csr2, dinv, featbf, bufA, h, 0.5f + 0.3f);
    spmm_bf16_kernel<1><<<spmmGrid, B, 0, stream>>>(offs, csr2, dinv, bufA, bufB, h, 0.15f);
    spmm_bf16_kernel<2><<<spmmGrid, B, 0, stream>>>(offs, csr2, dinv, bufB, nullptr, h, 0.05f);
}